// Round 10
// baseline (56.144 us; speedup 1.0000x reference)
//
#include <hip/hip_runtime.h>

#define BATCH 8192
#define DIM 128
#define NREL 1000
#define MARGIN 1.0f
#define GRID 1900        // max padded groups: (8192 + 7*1000)/8 = 1899
#define ORDER_CAP 15200  // GRID * 8

// ws layout (4 B units): partial[8192] | order[15200]
#define WS_PARTIAL 0
#define WS_ORDER 8192

// Fused single-block counting sort: zero + count + pad8-scan + init + scatter.
__global__ __launch_bounds__(1024) void sort_kernel(const int* __restrict__ r_idx,
                                                    int* __restrict__ order) {
  __shared__ int s_cnt[1024];
  __shared__ int s_cur[1024];
  __shared__ int s_wsum[16];
  const int tid = threadIdx.x, lane = tid & 63, wave = tid >> 6;
  s_cnt[tid] = 0;
  __syncthreads();
  int my[8];
#pragma unroll
  for (int k = 0; k < 8; ++k) {
    my[k] = r_idx[tid + k * 1024];
    atomicAdd(&s_cnt[my[k]], 1);
  }
  __syncthreads();
  const int c = (s_cnt[tid] + 7) & ~7;  // pad runs to multiple of 8
  int v = c;
#pragma unroll
  for (int o = 1; o < 64; o <<= 1) {
    int u = __shfl_up(v, o, 64);
    if (lane >= o) v += u;
  }
  if (lane == 63) s_wsum[wave] = v;
  __syncthreads();
  int woff = 0;
  for (int w = 0; w < wave; ++w) woff += s_wsum[w];
  s_cur[tid] = woff + v - c;
  for (int i = tid; i < ORDER_CAP; i += 1024) order[i] = -1;
  __syncthreads();
#pragma unroll
  for (int k = 0; k < 8; ++k) {
    int p = atomicAdd(&s_cur[my[k]], 1);
    order[p] = tid + k * 1024;
  }
}

__device__ inline float2 dvec(const float* __restrict__ b, int c0) {
  float2 h = *(const float2*)(b + c0);
  float2 r = *(const float2*)(b + DIM + c0);
  float2 t = *(const float2*)(b + 2 * DIM + c0);
  return make_float2(fabsf(h.x + r.x - t.x), fabsf(h.y + r.y - t.y));
}

// m204 general bijective XCD swizzle (nwg % 8 != 0 safe).
__device__ inline int xcd_swz(int phys, int nwg) {
  const int q = nwg >> 3, r = nwg & 7;
  const int xcd = phys & 7, o = phys >> 3;
  return (xcd < r ? xcd * (q + 1) : r * (q + 1) + (xcd - r) * q) + o;
}

// One block per 8-element same-relation group. Wave w covers W rows
// [32w, 32w+32) -> W read ONCE per 8 elements (~98 MB total).
// d staged by wave 0 in LANE-MAJOR stride-36 layout: unit l (rows 2l,2l+1)
// at l*36 floats; float4 writes hit quad (9l)%8 -> all 8 bank-quads,
// conflict-free. Hot-loop d reads are 2-address broadcasts. Epilogue uses
// register __shfl only (zero LDS reads -> no R6-style 32-way conflicts).
__global__ __launch_bounds__(256) void score_kernel(
    const float* __restrict__ pos_b, const float* __restrict__ neg_b,
    const int* __restrict__ r_idx, const float* __restrict__ rel_emb,
    const int* __restrict__ order, float* __restrict__ partial) {
  __shared__ float s_d[64 * 36];  // 9216 B
  __shared__ float s_ps[4][8];
  const int tid = threadIdx.x, lane = tid & 63, wave = tid >> 6;
  const int g = xcd_swz(blockIdx.x, GRID);

  int4 ea = *(const int4*)(order + g * 8);
  if (ea.x < 0) return;  // block-uniform: empty group, nobody reaches barrier
  int4 eb = *(const int4*)(order + g * 8 + 4);

  const int c0 = lane * 2;
  const int r = r_idx[ea.x];
  int e[8] = {ea.x, ea.y, ea.z, ea.w, eb.x, eb.y, eb.z, eb.w};
  bool val[8];
  float2 dp[8], dn[8];
  const float2 z = make_float2(0.f, 0.f);
#pragma unroll
  for (int i = 0; i < 8; ++i) {
    val[i] = e[i] >= 0;
    const int idx = val[i] ? e[i] : ea.x;
    dp[i] = val[i] ? dvec(pos_b + (size_t)idx * 3 * DIM, c0) : z;
    dn[i] = val[i] ? dvec(neg_b + (size_t)idx * 3 * DIM, c0) : z;
  }

  if (wave == 0) {
    // unit layout (36 floats): [0:8) dp row2l | [8:16) dn row2l |
    //                          [16:24) dp row2l+1 | [24:32) dn row2l+1 | pad
    float* u = &s_d[lane * 36];
    *(float4*)(u + 0)  = make_float4(dp[0].x, dp[1].x, dp[2].x, dp[3].x);
    *(float4*)(u + 4)  = make_float4(dp[4].x, dp[5].x, dp[6].x, dp[7].x);
    *(float4*)(u + 8)  = make_float4(dn[0].x, dn[1].x, dn[2].x, dn[3].x);
    *(float4*)(u + 12) = make_float4(dn[4].x, dn[5].x, dn[6].x, dn[7].x);
    *(float4*)(u + 16) = make_float4(dp[0].y, dp[1].y, dp[2].y, dp[3].y);
    *(float4*)(u + 20) = make_float4(dp[4].y, dp[5].y, dp[6].y, dp[7].y);
    *(float4*)(u + 24) = make_float4(dn[0].y, dn[1].y, dn[2].y, dn[3].y);
    *(float4*)(u + 28) = make_float4(dn[4].y, dn[5].y, dn[6].y, dn[7].y);
  }
  __syncthreads();

  const int colb = (lane & 31) * 4;
  const int rsel = lane >> 5;
  const float* W = rel_emb + (size_t)r * (DIM * DIM) +
                   (size_t)(wave * 32 + rsel) * DIM + colb;
  // iter it covers rows 32w+2it (+rsel): unit 16w+it, parity-half rsel*16
  const float* dbase = s_d + (wave * 16) * 36 + rsel * 16;

  const float4 fz = make_float4(0.f, 0.f, 0.f, 0.f);
  float4 ap[8], an[8];
#pragma unroll
  for (int i = 0; i < 8; ++i) { ap[i] = fz; an[i] = fz; }

#define FMA4(ACC, D, WV)          \
  ACC.x = fmaf(D, WV.x, ACC.x);   \
  ACC.y = fmaf(D, WV.y, ACC.y);   \
  ACC.z = fmaf(D, WV.z, ACC.z);   \
  ACC.w = fmaf(D, WV.w, ACC.w);

#pragma unroll 4
  for (int it = 0; it < 16; ++it) {
    float4 wv = *(const float4*)(W + (size_t)(it * 2) * DIM);
    const float* dd = dbase + it * 36;
    float4 p0 = *(const float4*)(dd + 0);   // broadcast
    float4 p1 = *(const float4*)(dd + 4);   // broadcast
    float4 n0 = *(const float4*)(dd + 8);   // broadcast
    float4 n1 = *(const float4*)(dd + 12);  // broadcast
    FMA4(ap[0], p0.x, wv) FMA4(ap[1], p0.y, wv)
    FMA4(ap[2], p0.z, wv) FMA4(ap[3], p0.w, wv)
    FMA4(ap[4], p1.x, wv) FMA4(ap[5], p1.y, wv)
    FMA4(ap[6], p1.z, wv) FMA4(ap[7], p1.w, wv)
    FMA4(an[0], n0.x, wv) FMA4(an[1], n0.y, wv)
    FMA4(an[2], n0.z, wv) FMA4(an[3], n0.w, wv)
    FMA4(an[4], n1.x, wv) FMA4(an[5], n1.y, wv)
    FMA4(an[6], n1.z, wv) FMA4(an[7], n1.w, wv)
  }
#undef FMA4

  // epilogue: lane lam owns cols 4lam..4lam+3; d for those cols lives in
  // lanes 2lam (.x,.y) and 2lam+1 (.x,.y) -> register __shfl, no LDS.
  const int sl0 = (lane & 31) * 2, sl1 = sl0 + 1;
  float s[8];
#pragma unroll
  for (int i = 0; i < 8; ++i) {
    float pa = __shfl(dp[i].x, sl0, 64), pb = __shfl(dp[i].y, sl0, 64);
    float pc = __shfl(dp[i].x, sl1, 64), pd = __shfl(dp[i].y, sl1, 64);
    float na = __shfl(dn[i].x, sl0, 64), nb = __shfl(dn[i].y, sl0, 64);
    float nc = __shfl(dn[i].x, sl1, 64), nd = __shfl(dn[i].y, sl1, 64);
    s[i] = ap[i].x * pa + ap[i].y * pb + ap[i].z * pc + ap[i].w * pd -
           (an[i].x * na + an[i].y * nb + an[i].z * nc + an[i].w * nd);
  }
#pragma unroll
  for (int o = 32; o > 0; o >>= 1) {
#pragma unroll
    for (int i = 0; i < 8; ++i) s[i] += __shfl_xor(s[i], o, 64);
  }
  if (lane == 0) {
#pragma unroll
    for (int i = 0; i < 8; ++i) s_ps[wave][i] = s[i];
  }
  __syncthreads();
  if (tid < 8) {
    const int ee = order[g * 8 + tid];
    if (ee >= 0)
      partial[ee] =
          s_ps[0][tid] + s_ps[1][tid] + s_ps[2][tid] + s_ps[3][tid];
  }
}

__global__ __launch_bounds__(256) void reduce_kernel(const float* __restrict__ partial,
                                                     float* __restrict__ out) {
  float acc = 0.f;
  for (int i = threadIdx.x; i < BATCH; i += 256) {
    float v = MARGIN + partial[i];
    acc += (v > 0.f) ? v : 0.f;
  }
#pragma unroll
  for (int o = 32; o > 0; o >>= 1) acc += __shfl_xor(acc, o, 64);
  __shared__ float s[4];
  const int lane = threadIdx.x & 63, wave = threadIdx.x >> 6;
  if (lane == 0) s[wave] = acc;
  __syncthreads();
  if (threadIdx.x == 0) out[0] = (s[0] + s[1] + s[2] + s[3]) * (1.0f / BATCH);
}

extern "C" void kernel_launch(void* const* d_in, const int* in_sizes, int n_in,
                              void* d_out, int out_size, void* d_ws, size_t ws_size,
                              hipStream_t stream) {
  const float* pos_b = (const float*)d_in[0];
  const float* neg_b = (const float*)d_in[1];
  const int* r_idx = (const int*)d_in[2];
  const float* rel_emb = (const float*)d_in[3];
  float* out = (float*)d_out;

  float* partial = (float*)d_ws + WS_PARTIAL;
  int* order = (int*)d_ws + WS_ORDER;

  sort_kernel<<<1, 1024, 0, stream>>>(r_idx, order);
  score_kernel<<<GRID, 256, 0, stream>>>(pos_b, neg_b, r_idx, rel_emb, order,
                                         partial);
  reduce_kernel<<<1, 256, 0, stream>>>(partial, out);
}

// Round 11
// 51.971 us; speedup vs baseline: 1.0803x; 1.0803x over previous
//
#include <hip/hip_runtime.h>

#define BATCH 8192
#define DIM 128
#define NREL 1000
#define MARGIN 1.0f

// ws layout (4 B units): partial[8192] | start[1024] | order[8192]
#define WS_PARTIAL 0
#define WS_START   8192
#define WS_ORDER   9216

// Single-block counting sort, exact offsets (no padding, no -1 init):
// count (LDS atomics) -> exclusive scan -> start[] to global -> scatter.
__global__ __launch_bounds__(1024) void sort_kernel(const int* __restrict__ r_idx,
                                                    int* __restrict__ start_g,
                                                    int* __restrict__ order) {
  __shared__ int s_cnt[1024];
  __shared__ int s_cur[1024];
  __shared__ int s_wsum[16];
  const int tid = threadIdx.x, lane = tid & 63, wave = tid >> 6;
  s_cnt[tid] = 0;
  __syncthreads();
  int my[8];
#pragma unroll
  for (int k = 0; k < 8; ++k) {
    my[k] = r_idx[tid + k * 1024];
    atomicAdd(&s_cnt[my[k]], 1);
  }
  __syncthreads();
  const int c = s_cnt[tid];
  int v = c;
#pragma unroll
  for (int o = 1; o < 64; o <<= 1) {
    int u = __shfl_up(v, o, 64);
    if (lane >= o) v += u;
  }
  if (lane == 63) s_wsum[wave] = v;
  __syncthreads();
  int woff = 0;
  for (int w = 0; w < wave; ++w) woff += s_wsum[w];
  const int my_start = woff + v - c;  // exclusive prefix
  start_g[tid] = my_start;            // start[1000] lands at 8192 (bins>=1000 empty)
  s_cur[tid] = my_start;
  __syncthreads();
#pragma unroll
  for (int k = 0; k < 8; ++k) {
    int p = atomicAdd(&s_cur[my[k]], 1);
    order[p] = tid + k * 1024;
  }
}

__device__ inline float2 dvec(const float* __restrict__ b, int c0) {
  float2 h = *(const float2*)(b + c0);
  float2 r = *(const float2*)(b + DIM + c0);
  float2 t = *(const float2*)(b + 2 * DIM + c0);
  return make_float2(fabsf(h.x + r.x - t.x), fabsf(h.y + r.y - t.y));
}

// One block per relation; loop over its elements in chunks of 8.
// W rows quarter per wave ([32w, 32w+32)); W read from L3 once per relation,
// chunk re-reads hit this CU's L1/L2. d staged cooperatively (each wave loads
// only its own 2 slots -> zero redundancy), LDS unit layout stride-36:
//   unit l (rows 2l, 2l+1): [0:8) dp row2l | [8:16) dn row2l |
//                           [16:24) dp row2l+1 | [24:32) dn row2l+1 | pad 4
// float4 loop reads are 2-address broadcasts; stage writes are float2 at
// lane-major stride 144 B (mild conflicts, once per chunk).
__global__ __launch_bounds__(256) void score_kernel(
    const float* __restrict__ pos_b, const float* __restrict__ neg_b,
    const float* __restrict__ rel_emb, const int* __restrict__ start,
    const int* __restrict__ order, float* __restrict__ partial) {
  __shared__ float s_d[64 * 36];  // 9216 B
  __shared__ float s_ps[4][8];
  const int tid = threadIdx.x, lane = tid & 63, wave = tid >> 6;
  // bijective XCD swizzle, NREL = 8 * 125 exactly
  const int r = (blockIdx.x & 7) * (NREL / 8) + (blockIdx.x >> 3);
  const int sA = start[r], sB = start[r + 1];
  if (sA == sB) return;  // block-uniform empty relation

  const int c0 = lane * 2;
  const int lam = lane & 31, rsel = lane >> 5;
  const int colb = lam * 4;
  const float* W = rel_emb + (size_t)r * (DIM * DIM) +
                   (size_t)(wave * 32 + rsel) * DIM + colb;
  const float* dbase = s_d + (wave * 16) * 36 + rsel * 16;

  for (int base = sA; base < sB; base += 8) {
    const int rem = sB - base;
    const int mm = rem < 8 ? rem : 8;

    // ---- cooperative d-stage: wave w fills slots 2w, 2w+1 ----
    {
      const int iA = 2 * wave, iB = iA + 1;
      const bool vA = iA < mm, vB = iB < mm;
      const float2 z = make_float2(0.f, 0.f);
      const int eA = vA ? order[base + iA] : 0;
      const int eB = vB ? order[base + iB] : 0;
      float2 dpA = vA ? dvec(pos_b + (size_t)eA * 3 * DIM, c0) : z;
      float2 dnA = vA ? dvec(neg_b + (size_t)eA * 3 * DIM, c0) : z;
      float2 dpB = vB ? dvec(pos_b + (size_t)eB * 3 * DIM, c0) : z;
      float2 dnB = vB ? dvec(neg_b + (size_t)eB * 3 * DIM, c0) : z;
      float* u = s_d + lane * 36;
      const int s2 = 2 * wave;
      *(float2*)(u + s2)      = make_float2(dpA.x, dpB.x);
      *(float2*)(u + 8 + s2)  = make_float2(dnA.x, dnB.x);
      *(float2*)(u + 16 + s2) = make_float2(dpA.y, dpB.y);
      *(float2*)(u + 24 + s2) = make_float2(dnA.y, dnB.y);
    }
    __syncthreads();

    // ---- FMA loop: wave's 32-row quarter, 8-deep W float4 pipeline ----
    const float4 fz = make_float4(0.f, 0.f, 0.f, 0.f);
    float4 ap[8], an[8];
#pragma unroll
    for (int i = 0; i < 8; ++i) { ap[i] = fz; an[i] = fz; }

#define FMA4(ACC, D, WV)          \
  ACC.x = fmaf(D, WV.x, ACC.x);   \
  ACC.y = fmaf(D, WV.y, ACC.y);   \
  ACC.z = fmaf(D, WV.z, ACC.z);   \
  ACC.w = fmaf(D, WV.w, ACC.w);

#pragma unroll 8
    for (int it = 0; it < 16; ++it) {
      float4 wv = *(const float4*)(W + (size_t)(it * 2) * DIM);
      const float* dd = dbase + it * 36;
      float4 p0 = *(const float4*)(dd + 0);   // broadcast
      float4 p1 = *(const float4*)(dd + 4);   // broadcast
      float4 n0 = *(const float4*)(dd + 8);   // broadcast
      float4 n1 = *(const float4*)(dd + 12);  // broadcast
      FMA4(ap[0], p0.x, wv) FMA4(ap[1], p0.y, wv)
      FMA4(ap[2], p0.z, wv) FMA4(ap[3], p0.w, wv)
      FMA4(ap[4], p1.x, wv) FMA4(ap[5], p1.y, wv)
      FMA4(ap[6], p1.z, wv) FMA4(ap[7], p1.w, wv)
      FMA4(an[0], n0.x, wv) FMA4(an[1], n0.y, wv)
      FMA4(an[2], n0.z, wv) FMA4(an[3], n0.w, wv)
      FMA4(an[4], n1.x, wv) FMA4(an[5], n1.y, wv)
      FMA4(an[6], n1.z, wv) FMA4(an[7], n1.w, wv)
    }
#undef FMA4

    // ---- epilogue: dot colaccs with d (d from LDS, ~8-way, 16 reads) ----
    float s[8];
#pragma unroll
    for (int i = 0; i < 8; ++i) s[i] = 0.f;
#define EPI(K, COMP)                                              \
    {                                                             \
      const int cc = colb + K;                                    \
      const float* dd = s_d + (cc >> 1) * 36 + (cc & 1) * 16;     \
      float4 plo = *(const float4*)(dd + 0);                      \
      float4 phi = *(const float4*)(dd + 4);                      \
      float4 nlo = *(const float4*)(dd + 8);                      \
      float4 nhi = *(const float4*)(dd + 12);                     \
      s[0] += ap[0].COMP * plo.x - an[0].COMP * nlo.x;            \
      s[1] += ap[1].COMP * plo.y - an[1].COMP * nlo.y;            \
      s[2] += ap[2].COMP * plo.z - an[2].COMP * nlo.z;            \
      s[3] += ap[3].COMP * plo.w - an[3].COMP * nlo.w;            \
      s[4] += ap[4].COMP * phi.x - an[4].COMP * nhi.x;            \
      s[5] += ap[5].COMP * phi.y - an[5].COMP * nhi.y;            \
      s[6] += ap[6].COMP * phi.z - an[6].COMP * nhi.z;            \
      s[7] += ap[7].COMP * phi.w - an[7].COMP * nhi.w;            \
    }
    EPI(0, x) EPI(1, y) EPI(2, z) EPI(3, w)
#undef EPI

#pragma unroll
    for (int o = 32; o > 0; o >>= 1) {
#pragma unroll
      for (int i = 0; i < 8; ++i) s[i] += __shfl_xor(s[i], o, 64);
    }
    if (lane == 0) {
#pragma unroll
      for (int i = 0; i < 8; ++i) s_ps[wave][i] = s[i];
    }
    __syncthreads();
    if (tid < mm)
      partial[order[base + tid]] =
          s_ps[0][tid] + s_ps[1][tid] + s_ps[2][tid] + s_ps[3][tid];
    // next chunk's stage writes s_d (disjoint from s_ps); s_ps rewritten only
    // after every thread passes the next chunk's post-stage barrier -> safe.
  }
}

__global__ __launch_bounds__(256) void reduce_kernel(const float* __restrict__ partial,
                                                     float* __restrict__ out) {
  float acc = 0.f;
  for (int i = threadIdx.x; i < BATCH; i += 256) {
    float v = MARGIN + partial[i];
    acc += (v > 0.f) ? v : 0.f;
  }
#pragma unroll
  for (int o = 32; o > 0; o >>= 1) acc += __shfl_xor(acc, o, 64);
  __shared__ float s[4];
  const int lane = threadIdx.x & 63, wave = threadIdx.x >> 6;
  if (lane == 0) s[wave] = acc;
  __syncthreads();
  if (threadIdx.x == 0) out[0] = (s[0] + s[1] + s[2] + s[3]) * (1.0f / BATCH);
}

extern "C" void kernel_launch(void* const* d_in, const int* in_sizes, int n_in,
                              void* d_out, int out_size, void* d_ws, size_t ws_size,
                              hipStream_t stream) {
  const float* pos_b = (const float*)d_in[0];
  const float* neg_b = (const float*)d_in[1];
  const int* r_idx = (const int*)d_in[2];
  const float* rel_emb = (const float*)d_in[3];
  float* out = (float*)d_out;

  float* partial = (float*)d_ws + WS_PARTIAL;
  int* start = (int*)d_ws + WS_START;
  int* order = (int*)d_ws + WS_ORDER;

  sort_kernel<<<1, 1024, 0, stream>>>(r_idx, start, order);
  score_kernel<<<NREL, 256, 0, stream>>>(pos_b, neg_b, rel_emb, start, order,
                                         partial);
  reduce_kernel<<<1, 256, 0, stream>>>(partial, out);
}